// Round 1
// baseline (1786.569 us; speedup 1.0000x reference)
//
#include <hip/hip_runtime.h>
#include <hip/hip_bf16.h>
#include <math.h>

#define N_NODES 100000
#define N_EDGES 1000000
#define NEG_SLOPE 0.2f

// ---------------- CSR build ----------------
__global__ void hist_kernel(const int* __restrict__ dst, int* __restrict__ counts) {
    int e = blockIdx.x * blockDim.x + threadIdx.x;
    if (e < N_EDGES) atomicAdd(&counts[dst[e]], 1);
}

// single block, 1024 threads: exclusive scan of counts[N] -> row_ptr[N+1], cursor[N]
__global__ void scan_kernel(const int* __restrict__ counts,
                            int* __restrict__ row_ptr, int* __restrict__ cursor) {
    __shared__ int ssum[1024];
    int t = threadIdx.x;
    const int C = (N_NODES + 1023) / 1024;  // 98
    int beg = t * C;
    int end = beg + C < N_NODES ? beg + C : N_NODES;
    int s = 0;
    for (int i = beg; i < end; ++i) s += counts[i];
    ssum[t] = s;
    __syncthreads();
    int local = s;
    for (int off = 1; off < 1024; off <<= 1) {
        int v = (t >= off) ? ssum[t - off] : 0;
        __syncthreads();
        ssum[t] += v;
        __syncthreads();
    }
    int run = ssum[t] - local;  // exclusive prefix
    for (int i = beg; i < end; ++i) {
        row_ptr[i] = run;
        cursor[i]  = run;
        run += counts[i];
    }
    if (t == 1023) row_ptr[N_NODES] = ssum[1023];
}

__global__ void scatter_kernel(const int* __restrict__ src, const int* __restrict__ dst,
                               int* __restrict__ cursor, int* __restrict__ srcs) {
    int e = blockIdx.x * blockDim.x + threadIdx.x;
    if (e < N_EDGES) {
        int pos = atomicAdd(&cursor[dst[e]], 1);
        srcs[pos] = src[e];
    }
}

// ---------------- h0 = relu(x @ W0)  [N,64]@[64,32] ----------------
__global__ void h0_kernel(const float* __restrict__ x, const float* __restrict__ W0,
                          float* __restrict__ h) {
    int tid = blockIdx.x * blockDim.x + threadIdx.x;
    int col = tid & 31;
    int row = tid >> 5;
    if (row >= N_NODES) return;
    const float* xr = x + row * 64;
    float acc = 0.f;
#pragma unroll
    for (int k = 0; k < 64; ++k) acc = fmaf(xr[k], W0[k * 32 + col], acc);
    h[row * 32 + col] = fmaxf(acc, 0.f);
}

// ---------------- fused xl|xr|skip matmul ----------------
// out[N,384]: cols 0-127 = h@Wl+bl, 128-255 = h@Wr+br, 256-383 = h@Ws+bs+cb
// BM=128 rows, BN=128 cols (one section), BK=16, 256 threads, 8x8 per thread.
template <int DIN>
__global__ __launch_bounds__(256) void mm3_kernel(
    const float* __restrict__ A,  // [N, DIN]
    const float* __restrict__ Wl, const float* __restrict__ Wr, const float* __restrict__ Ws,
    const float* __restrict__ bl, const float* __restrict__ br, const float* __restrict__ bs,
    const float* __restrict__ cb,
    float* __restrict__ out) {
    __shared__ float As[16][132];  // transposed A tile (k-major), +4 pad
    __shared__ float Bs[16][128];

    const int sec = blockIdx.y;  // 0=Wl,1=Wr,2=Ws
    const float* W = (sec == 0) ? Wl : (sec == 1) ? Wr : Ws;
    const int row0 = blockIdx.x * 128;
    const int tid = threadIdx.x;
    const int tx = tid & 15, ty = tid >> 4;

    float acc[8][8];
#pragma unroll
    for (int i = 0; i < 8; ++i)
#pragma unroll
        for (int j = 0; j < 8; ++j) acc[i][j] = 0.f;

    for (int k0 = 0; k0 < DIN; k0 += 16) {
        // A tile: 128 rows x 16 k -> 512 float4, 2 per thread
#pragma unroll
        for (int i = 0; i < 2; ++i) {
            int idx = tid + i * 256;   // 0..511
            int kq = idx & 3;          // float4 slot along k
            int r = idx >> 2;          // row 0..127
            int row = row0 + r;
            float4 v = make_float4(0.f, 0.f, 0.f, 0.f);
            if (row < N_NODES) v = *(const float4*)&A[(size_t)row * DIN + k0 + kq * 4];
            As[kq * 4 + 0][r] = v.x;
            As[kq * 4 + 1][r] = v.y;
            As[kq * 4 + 2][r] = v.z;
            As[kq * 4 + 3][r] = v.w;
        }
        // B tile: 16 k x 128 cols -> 512 float4, 2 per thread
#pragma unroll
        for (int i = 0; i < 2; ++i) {
            int idx = tid + i * 256;
            int c4 = idx & 31;
            int k = idx >> 5;
            *(float4*)&Bs[k][c4 * 4] = *(const float4*)&W[(k0 + k) * 128 + c4 * 4];
        }
        __syncthreads();
#pragma unroll
        for (int k = 0; k < 16; ++k) {
            float a[8], b[8];
            *(float4*)&a[0] = *(const float4*)&As[k][ty * 8];
            *(float4*)&a[4] = *(const float4*)&As[k][ty * 8 + 4];
            *(float4*)&b[0] = *(const float4*)&Bs[k][tx * 8];
            *(float4*)&b[4] = *(const float4*)&Bs[k][tx * 8 + 4];
#pragma unroll
            for (int i = 0; i < 8; ++i)
#pragma unroll
                for (int j = 0; j < 8; ++j) acc[i][j] = fmaf(a[i], b[j], acc[i][j]);
        }
        __syncthreads();
    }

    float bias[8];
#pragma unroll
    for (int j = 0; j < 8; ++j) {
        int c = tx * 8 + j;
        bias[j] = (sec == 0) ? bl[c] : (sec == 1) ? br[c] : (bs[c] + cb[c]);
    }
#pragma unroll
    for (int i = 0; i < 8; ++i) {
        int row = row0 + ty * 8 + i;
        if (row < N_NODES) {
            float* o = &out[(size_t)row * 384 + sec * 128 + tx * 8];
            float4 v0 = make_float4(acc[i][0] + bias[0], acc[i][1] + bias[1],
                                    acc[i][2] + bias[2], acc[i][3] + bias[3]);
            float4 v1 = make_float4(acc[i][4] + bias[4], acc[i][5] + bias[5],
                                    acc[i][6] + bias[6], acc[i][7] + bias[7]);
            *(float4*)&o[0] = v0;
            *(float4*)&o[4] = v1;
        }
    }
}

// ---------------- GATv2 aggregation: one wave (64 lanes) per node ----------------
// buf[N,384] = xl | xr | skip.  Per lane: channels 2*lane, 2*lane+1 (head = lane>>4).
__global__ __launch_bounds__(256) void agg_kernel(
    const float* __restrict__ buf, const int* __restrict__ row_ptr,
    const int* __restrict__ srcs, const float* __restrict__ att,
    float* __restrict__ out, int do_relu, int do_norm) {
    int wave = (blockIdx.x * blockDim.x + threadIdx.x) >> 6;
    int lane = threadIdx.x & 63;
    if (wave >= N_NODES) return;
    const int n = wave;
    const float2* b2 = (const float2*)buf;

    float2 xr2 = b2[(size_t)n * 192 + 64 + lane];
    float2 at2 = ((const float2*)att)[lane];

    float m = -INFINITY, l = 0.f;
    float2 acc = make_float2(0.f, 0.f);
    int beg = row_ptr[n], end = row_ptr[n + 1];
    for (int e = beg; e < end; ++e) {
        int s = srcs[e];
        float2 xl2 = b2[(size_t)s * 192 + lane];
        float ex = xl2.x + xr2.x;
        float ey = xl2.y + xr2.y;
        float lx = ex > 0.f ? ex : NEG_SLOPE * ex;
        float ly = ey > 0.f ? ey : NEG_SLOPE * ey;
        float p = lx * at2.x + ly * at2.y;
        // reduce over the 16-lane head group
        p += __shfl_xor(p, 1);
        p += __shfl_xor(p, 2);
        p += __shfl_xor(p, 4);
        p += __shfl_xor(p, 8);
        float mn = fmaxf(m, p);
        float sc = __expf(m - mn);
        float w = __expf(p - mn);
        l = l * sc + w;
        acc.x = acc.x * sc + xl2.x * w;
        acc.y = acc.y * sc + xl2.y * w;
        m = mn;
    }
    float inv = (l > 0.f) ? 1.f / l : 0.f;
    float2 sk = b2[(size_t)n * 192 + 128 + lane];
    float ox = acc.x * inv + sk.x;
    float oy = acc.y * inv + sk.y;
    if (do_relu) {
        ox = fmaxf(ox, 0.f);
        oy = fmaxf(oy, 0.f);
    }
    if (do_norm) {
        float ss = ox * ox + oy * oy;
        for (int off = 1; off < 64; off <<= 1) ss += __shfl_xor(ss, off);
        float r = 1.0f / sqrtf(ss);
        ox *= r;
        oy *= r;
    }
    ((float2*)out)[(size_t)n * 64 + lane] = make_float2(ox, oy);
}

// ---------------- launch ----------------
extern "C" void kernel_launch(void* const* d_in, const int* in_sizes, int n_in,
                              void* d_out, int out_size, void* d_ws, size_t ws_size,
                              hipStream_t stream) {
    const float* x = (const float*)d_in[0];
    const int* ei = (const int*)d_in[1];
    const int* src = ei;
    const int* dst = ei + N_EDGES;
    const float* W0 = (const float*)d_in[2];

    // per-layer params: Wl bl Wr br att cb Ws bs, starting at index 3
    const float* f_p[8];
    const float* m_p[8];
    const float* l_p[8];
    for (int i = 0; i < 8; ++i) f_p[i] = (const float*)d_in[3 + i];
    for (int i = 0; i < 8; ++i) m_p[i] = (const float*)d_in[11 + i];
    for (int i = 0; i < 8; ++i) l_p[i] = (const float*)d_in[19 + i];
    // indices: 0=Wl 1=bl 2=Wr 3=br 4=att 5=cb 6=Ws 7=bs

    char* ws = (char*)d_ws;
    float* buf = (float*)ws;       ws += (size_t)N_NODES * 384 * 4;  // 153.6 MB
    float* h = (float*)ws;         ws += (size_t)N_NODES * 128 * 4;  // 51.2 MB
    int* row_ptr = (int*)ws;       ws += (size_t)(N_NODES + 1) * 4;
    int* cursor = (int*)ws;        ws += (size_t)N_NODES * 4;
    int* counts = (int*)ws;        ws += (size_t)N_NODES * 4;
    int* srcs = (int*)ws;          ws += (size_t)N_EDGES * 4;

    hipMemsetAsync(counts, 0, (size_t)N_NODES * 4, stream);
    hist_kernel<<<(N_EDGES + 255) / 256, 256, 0, stream>>>(dst, counts);
    scan_kernel<<<1, 1024, 0, stream>>>(counts, row_ptr, cursor);
    scatter_kernel<<<(N_EDGES + 255) / 256, 256, 0, stream>>>(src, dst, cursor, srcs);

    h0_kernel<<<(N_NODES * 32) / 256, 256, 0, stream>>>(x, W0, h);

    dim3 gmm((N_NODES + 127) / 128, 3);
    const int gagg = (N_NODES * 64) / 256;
    float* out = (float*)d_out;

    // layer f (din=32), relu
    mm3_kernel<32><<<gmm, 256, 0, stream>>>(h, f_p[0], f_p[2], f_p[6], f_p[1], f_p[3],
                                            f_p[7], f_p[5], buf);
    agg_kernel<<<gagg, 256, 0, stream>>>(buf, row_ptr, srcs, f_p[4], h, 1, 0);

    // 3x layer m (din=128, shared weights), relu
    for (int it = 0; it < 3; ++it) {
        mm3_kernel<128><<<gmm, 256, 0, stream>>>(h, m_p[0], m_p[2], m_p[6], m_p[1], m_p[3],
                                                 m_p[7], m_p[5], buf);
        agg_kernel<<<gagg, 256, 0, stream>>>(buf, row_ptr, srcs, m_p[4], h, 1, 0);
    }

    // layer l (din=128), no relu, L2 normalize, write to d_out
    mm3_kernel<128><<<gmm, 256, 0, stream>>>(h, l_p[0], l_p[2], l_p[6], l_p[1], l_p[3],
                                             l_p[7], l_p[5], buf);
    agg_kernel<<<gagg, 256, 0, stream>>>(buf, row_ptr, srcs, l_p[4], out, 0, 1);
}

// Round 2
// 1547.947 us; speedup vs baseline: 1.1542x; 1.1542x over previous
//
#include <hip/hip_runtime.h>
#include <hip/hip_bf16.h>
#include <math.h>

#define N_NODES 100000
#define N_EDGES 1000000
#define NEG_SLOPE 0.2f
#define SCAN_NB 98  // ceil(100000/1024)

// ---------------- CSR build ----------------
__global__ void hist_kernel(const int* __restrict__ dst, int* __restrict__ counts) {
    int e = blockIdx.x * blockDim.x + threadIdx.x;
    if (e < N_EDGES) atomicAdd(&counts[dst[e]], 1);
}

// Phase A: block b sums counts[b*1024 .. b*1024+1023] -> bsum[b]
__global__ void scan_partial(const int* __restrict__ counts, int* __restrict__ bsum) {
    __shared__ int red[256];
    int b = blockIdx.x;
    int base = b * 1024;
    int s = 0;
    for (int i = threadIdx.x; i < 1024; i += 256) {
        int gi = base + i;
        s += (gi < N_NODES) ? counts[gi] : 0;
    }
    red[threadIdx.x] = s;
    __syncthreads();
    for (int off = 128; off > 0; off >>= 1) {
        if (threadIdx.x < off) red[threadIdx.x] += red[threadIdx.x + off];
        __syncthreads();
    }
    if (threadIdx.x == 0) bsum[b] = red[0];
}

// Phase B: single tiny block scans the 98 block sums -> boff (exclusive), row_ptr[N]=total
__global__ void scan_bsum(const int* __restrict__ bsum, int* __restrict__ boff,
                          int* __restrict__ row_ptr) {
    __shared__ int s[128];
    int t = threadIdx.x;
    int v = (t < SCAN_NB) ? bsum[t] : 0;
    s[t] = v;
    __syncthreads();
    for (int off = 1; off < 128; off <<= 1) {
        int u = (t >= off) ? s[t - off] : 0;
        __syncthreads();
        s[t] += u;
        __syncthreads();
    }
    if (t < SCAN_NB) boff[t] = s[t] - v;  // exclusive prefix
    if (t == 127) row_ptr[N_NODES] = s[127];
}

// Phase C: block b scans its own 1024 counts with offset boff[b] -> row_ptr, cursor
__global__ void scan_final(const int* __restrict__ counts, const int* __restrict__ boff,
                           int* __restrict__ row_ptr, int* __restrict__ cursor) {
    __shared__ int tsum[256];
    int b = blockIdx.x;
    int base = b * 1024;
    int v[4];
    int local = 0;
#pragma unroll
    for (int j = 0; j < 4; ++j) {
        int gi = base + threadIdx.x * 4 + j;
        v[j] = (gi < N_NODES) ? counts[gi] : 0;
        local += v[j];
    }
    tsum[threadIdx.x] = local;
    __syncthreads();
    for (int off = 1; off < 256; off <<= 1) {
        int u = (threadIdx.x >= off) ? tsum[threadIdx.x - off] : 0;
        __syncthreads();
        tsum[threadIdx.x] += u;
        __syncthreads();
    }
    int run = boff[b] + tsum[threadIdx.x] - local;
#pragma unroll
    for (int j = 0; j < 4; ++j) {
        int gi = base + threadIdx.x * 4 + j;
        if (gi < N_NODES) {
            row_ptr[gi] = run;
            cursor[gi] = run;
            run += v[j];
        }
    }
}

__global__ void scatter_kernel(const int* __restrict__ src, const int* __restrict__ dst,
                               int* __restrict__ cursor, int* __restrict__ srcs) {
    int e = blockIdx.x * blockDim.x + threadIdx.x;
    if (e < N_EDGES) {
        int pos = atomicAdd(&cursor[dst[e]], 1);
        srcs[pos] = src[e];
    }
}

// ---------------- h0 = relu(x @ W0)  [N,64]@[64,32] ----------------
__global__ void h0_kernel(const float* __restrict__ x, const float* __restrict__ W0,
                          float* __restrict__ h) {
    int tid = blockIdx.x * blockDim.x + threadIdx.x;
    int col = tid & 31;
    int row = tid >> 5;
    if (row >= N_NODES) return;
    const float* xr = x + row * 64;
    float acc = 0.f;
#pragma unroll
    for (int k = 0; k < 64; ++k) acc = fmaf(xr[k], W0[k * 32 + col], acc);
    h[row * 32 + col] = fmaxf(acc, 0.f);
}

// ---------------- fused xl|xr|skip matmul ----------------
// out[N,384]: cols 0-127 = h@Wl+bl, 128-255 = h@Wr+br, 256-383 = h@Ws+bs+cb
template <int DIN>
__global__ __launch_bounds__(256) void mm3_kernel(
    const float* __restrict__ A,  // [N, DIN]
    const float* __restrict__ Wl, const float* __restrict__ Wr, const float* __restrict__ Ws,
    const float* __restrict__ bl, const float* __restrict__ br, const float* __restrict__ bs,
    const float* __restrict__ cb,
    float* __restrict__ out) {
    __shared__ float As[16][132];
    __shared__ float Bs[16][128];

    const int sec = blockIdx.y;  // 0=Wl,1=Wr,2=Ws
    const float* W = (sec == 0) ? Wl : (sec == 1) ? Wr : Ws;
    const int row0 = blockIdx.x * 128;
    const int tid = threadIdx.x;
    const int tx = tid & 15, ty = tid >> 4;

    float acc[8][8];
#pragma unroll
    for (int i = 0; i < 8; ++i)
#pragma unroll
        for (int j = 0; j < 8; ++j) acc[i][j] = 0.f;

    for (int k0 = 0; k0 < DIN; k0 += 16) {
#pragma unroll
        for (int i = 0; i < 2; ++i) {
            int idx = tid + i * 256;
            int kq = idx & 3;
            int r = idx >> 2;
            int row = row0 + r;
            float4 v = make_float4(0.f, 0.f, 0.f, 0.f);
            if (row < N_NODES) v = *(const float4*)&A[(size_t)row * DIN + k0 + kq * 4];
            As[kq * 4 + 0][r] = v.x;
            As[kq * 4 + 1][r] = v.y;
            As[kq * 4 + 2][r] = v.z;
            As[kq * 4 + 3][r] = v.w;
        }
#pragma unroll
        for (int i = 0; i < 2; ++i) {
            int idx = tid + i * 256;
            int c4 = idx & 31;
            int k = idx >> 5;
            *(float4*)&Bs[k][c4 * 4] = *(const float4*)&W[(k0 + k) * 128 + c4 * 4];
        }
        __syncthreads();
#pragma unroll
        for (int k = 0; k < 16; ++k) {
            float a[8], b[8];
            *(float4*)&a[0] = *(const float4*)&As[k][ty * 8];
            *(float4*)&a[4] = *(const float4*)&As[k][ty * 8 + 4];
            *(float4*)&b[0] = *(const float4*)&Bs[k][tx * 8];
            *(float4*)&b[4] = *(const float4*)&Bs[k][tx * 8 + 4];
#pragma unroll
            for (int i = 0; i < 8; ++i)
#pragma unroll
                for (int j = 0; j < 8; ++j) acc[i][j] = fmaf(a[i], b[j], acc[i][j]);
        }
        __syncthreads();
    }

    float bias[8];
#pragma unroll
    for (int j = 0; j < 8; ++j) {
        int c = tx * 8 + j;
        bias[j] = (sec == 0) ? bl[c] : (sec == 1) ? br[c] : (bs[c] + cb[c]);
    }
#pragma unroll
    for (int i = 0; i < 8; ++i) {
        int row = row0 + ty * 8 + i;
        if (row < N_NODES) {
            float* o = &out[(size_t)row * 384 + sec * 128 + tx * 8];
            float4 v0 = make_float4(acc[i][0] + bias[0], acc[i][1] + bias[1],
                                    acc[i][2] + bias[2], acc[i][3] + bias[3]);
            float4 v1 = make_float4(acc[i][4] + bias[4], acc[i][5] + bias[5],
                                    acc[i][6] + bias[6], acc[i][7] + bias[7]);
            *(float4*)&o[0] = v0;
            *(float4*)&o[4] = v1;
        }
    }
}

// ---------------- GATv2 aggregation: one wave (64 lanes) per node ----------------
__global__ __launch_bounds__(256) void agg_kernel(
    const float* __restrict__ buf, const int* __restrict__ row_ptr,
    const int* __restrict__ srcs, const float* __restrict__ att,
    float* __restrict__ out, int do_relu, int do_norm) {
    int wave = (blockIdx.x * blockDim.x + threadIdx.x) >> 6;
    int lane = threadIdx.x & 63;
    if (wave >= N_NODES) return;
    const int n = wave;
    const float2* b2 = (const float2*)buf;

    float2 xr2 = b2[(size_t)n * 192 + 64 + lane];
    float2 at2 = ((const float2*)att)[lane];

    float m = -INFINITY, l = 0.f;
    float2 acc = make_float2(0.f, 0.f);
    int beg = row_ptr[n], end = row_ptr[n + 1];
    for (int e = beg; e < end; ++e) {
        int s = srcs[e];
        float2 xl2 = b2[(size_t)s * 192 + lane];
        float ex = xl2.x + xr2.x;
        float ey = xl2.y + xr2.y;
        float lx = ex > 0.f ? ex : NEG_SLOPE * ex;
        float ly = ey > 0.f ? ey : NEG_SLOPE * ey;
        float p = lx * at2.x + ly * at2.y;
        p += __shfl_xor(p, 1);
        p += __shfl_xor(p, 2);
        p += __shfl_xor(p, 4);
        p += __shfl_xor(p, 8);
        float mn = fmaxf(m, p);
        float sc = __expf(m - mn);
        float w = __expf(p - mn);
        l = l * sc + w;
        acc.x = acc.x * sc + xl2.x * w;
        acc.y = acc.y * sc + xl2.y * w;
        m = mn;
    }
    float inv = (l > 0.f) ? 1.f / l : 0.f;
    float2 sk = b2[(size_t)n * 192 + 128 + lane];
    float ox = acc.x * inv + sk.x;
    float oy = acc.y * inv + sk.y;
    if (do_relu) {
        ox = fmaxf(ox, 0.f);
        oy = fmaxf(oy, 0.f);
    }
    if (do_norm) {
        float ss = ox * ox + oy * oy;
        for (int off = 1; off < 64; off <<= 1) ss += __shfl_xor(ss, off);
        float r = 1.0f / sqrtf(ss);
        ox *= r;
        oy *= r;
    }
    ((float2*)out)[(size_t)n * 64 + lane] = make_float2(ox, oy);
}

// ---------------- launch ----------------
extern "C" void kernel_launch(void* const* d_in, const int* in_sizes, int n_in,
                              void* d_out, int out_size, void* d_ws, size_t ws_size,
                              hipStream_t stream) {
    const float* x = (const float*)d_in[0];
    const int* ei = (const int*)d_in[1];
    const int* src = ei;
    const int* dst = ei + N_EDGES;
    const float* W0 = (const float*)d_in[2];

    const float* f_p[8];
    const float* m_p[8];
    const float* l_p[8];
    for (int i = 0; i < 8; ++i) f_p[i] = (const float*)d_in[3 + i];
    for (int i = 0; i < 8; ++i) m_p[i] = (const float*)d_in[11 + i];
    for (int i = 0; i < 8; ++i) l_p[i] = (const float*)d_in[19 + i];
    // indices: 0=Wl 1=bl 2=Wr 3=br 4=att 5=cb 6=Ws 7=bs

    char* ws = (char*)d_ws;
    float* buf = (float*)ws;       ws += (size_t)N_NODES * 384 * 4;  // 153.6 MB
    float* h = (float*)ws;         ws += (size_t)N_NODES * 128 * 4;  // 51.2 MB
    int* row_ptr = (int*)ws;       ws += (size_t)(N_NODES + 1) * 4;
    int* cursor = (int*)ws;        ws += (size_t)N_NODES * 4;
    int* counts = (int*)ws;        ws += (size_t)N_NODES * 4;
    int* srcs = (int*)ws;          ws += (size_t)N_EDGES * 4;
    int* bsum = (int*)ws;          ws += (size_t)SCAN_NB * 4;
    int* boff = (int*)ws;          ws += (size_t)SCAN_NB * 4;

    hipMemsetAsync(counts, 0, (size_t)N_NODES * 4, stream);
    hist_kernel<<<(N_EDGES + 255) / 256, 256, 0, stream>>>(dst, counts);
    scan_partial<<<SCAN_NB, 256, 0, stream>>>(counts, bsum);
    scan_bsum<<<1, 128, 0, stream>>>(bsum, boff, row_ptr);
    scan_final<<<SCAN_NB, 256, 0, stream>>>(counts, boff, row_ptr, cursor);
    scatter_kernel<<<(N_EDGES + 255) / 256, 256, 0, stream>>>(src, dst, cursor, srcs);

    h0_kernel<<<(N_NODES * 32) / 256, 256, 0, stream>>>(x, W0, h);

    dim3 gmm((N_NODES + 127) / 128, 3);
    const int gagg = (N_NODES * 64) / 256;
    float* out = (float*)d_out;

    // layer f (din=32), relu
    mm3_kernel<32><<<gmm, 256, 0, stream>>>(h, f_p[0], f_p[2], f_p[6], f_p[1], f_p[3],
                                            f_p[7], f_p[5], buf);
    agg_kernel<<<gagg, 256, 0, stream>>>(buf, row_ptr, srcs, f_p[4], h, 1, 0);

    // 3x layer m (din=128, shared weights), relu
    for (int it = 0; it < 3; ++it) {
        mm3_kernel<128><<<gmm, 256, 0, stream>>>(h, m_p[0], m_p[2], m_p[6], m_p[1], m_p[3],
                                                 m_p[7], m_p[5], buf);
        agg_kernel<<<gagg, 256, 0, stream>>>(buf, row_ptr, srcs, m_p[4], h, 1, 0);
    }

    // layer l (din=128), no relu, L2 normalize, write to d_out
    mm3_kernel<128><<<gmm, 256, 0, stream>>>(h, l_p[0], l_p[2], l_p[6], l_p[1], l_p[3],
                                             l_p[7], l_p[5], buf);
    agg_kernel<<<gagg, 256, 0, stream>>>(buf, row_ptr, srcs, l_p[4], out, 0, 1);
}